// Round 4
// baseline (166.834 us; speedup 1.0000x reference)
//
#include <hip/hip_runtime.h>

#define NRBF 20
#define FOUT 16
#define NA 768
#define NB 4
#define NT 48            // m-tiles per row (768/16)
#define TPW 12           // tiles per wave (NT/4)

// Round-7: revert R6's symmetry (mirror stores regressed); keep R6's
// swapped-operand MFMA (dense stores); make each wave's write stream
// contiguous; nontemporal store hint; raw-HW sqrt.
//
//   D = W * RBF^T per 16-m tile via mfma_f32_16x16x32_f16.
//   A-frag: lane holds W[f = l&15][k = 8*(l>>4)+j], zero-padded k>=20.
//   B-frag: lane holds rbf[k = 8*(l>>4)+j][m = l&15] (geometric recurrence,
//           7 serial steps per lane, k-parallel across the 4 lane-groups).
//   D: row = f = 4*(l>>4)+reg, col = m = l&15  -> lane stores f32x4 of 4
//   consecutive f for one m: ONE global_store_dwordx4 per tile, the wave
//   covering a fully-dense (lane-permuted) 1KB span. Layout HW-validated in
//   round 6 (passed, absmax unchanged).
//
//   Wave w owns tiles [w*12, w*12+12): monotone 12KB write stream per wave
//   (fill-like), vs the old strided t*4+w hopping 4KB between stores.
//   Nontemporal: output is write-once, never re-read -> don't retain in L2.
//   sqrt via __builtin_amdgcn_sqrtf (raw v_sqrt_f32, ~1 ULP): skips the OCML
//   correctly-rounded fixup sequence; tolerance headroom is ~100x.
//
// RBF recurrence (telescoped -10(d-0.1k)^2), segment-start k0 = 8g:
//   r_{k0} = e^{-10(d-0.1k0)^2}, ratio t_{k0+1} = e^{2d-0.2k0-0.1}, t *= e^{-0.2}.

typedef _Float16 f16x8 __attribute__((ext_vector_type(8)));
typedef float    f32x4 __attribute__((ext_vector_type(4)));

__global__ __launch_bounds__(256, 8) void cfconv_kernel(
    const float* __restrict__ coords,  // [NB, NA, 3] fp32
    const float* __restrict__ Ww,      // [FOUT, NRBF] fp32
    const float* __restrict__ Wb,      // [FOUT] fp32
    float* __restrict__ out)           // [NB, NA, NA, FOUT] fp32
{
    __shared__ float cm[NA * 3];       // batch's m-coordinates

    const int tid = threadIdx.x;
    const int n   = blockIdx.x;
    const int b   = blockIdx.y;

    const float* cb = coords + (size_t)b * NA * 3;
    for (int i = tid; i < NA * 3; i += 256) cm[i] = cb[i];
    __syncthreads();

    const int w  = tid >> 6;   // wave id 0..3 -> owns tiles w*12 .. w*12+11
    const int l  = tid & 63;
    const int mi = l & 15;     // m sub-index (B col / D col)
    const int g  = l >> 4;     // k-group; lane's D rows are f = 4g+0..3

    // A fragment = W[f = mi][k = 8g+j], zero-padded k >= 20 (L2-hot loads)
    f16x8 afrag;
    #pragma unroll
    for (int j = 0; j < 8; ++j) {
        const int k = g * 8 + j;
        afrag[j] = (k < NRBF) ? (_Float16)Ww[mi * NRBF + k] : (_Float16)0.0f;
    }
    // C-in rows are f = 4g+r -> bias per reg
    const f32x4 cinit = { Wb[4*g+0], Wb[4*g+1], Wb[4*g+2], Wb[4*g+3] };

    const float xn = cb[n*3+0];   // block-uniform -> scalar loads
    const float yn = cb[n*3+1];
    const float zn = cb[n*3+2];

    const float mu0  = 0.1f * (8 * g);          // segment-start mu
    const float tcst = 0.2f * (8 * g) + 0.1f;   // t_{k0+1} exponent offset
    const float u    = 0.81873075308f;          // e^{-0.2}

    // lane's store base for tile t: orow + t*1KB + (mi*FOUT + 4g)*4B
    float* obase = out + (((size_t)b * NA + n) * NA + mi) * FOUT + 4 * g;

    #pragma unroll 2
    for (int tt = 0; tt < TPW; ++tt) {
        const int t = w * TPW + tt;
        const int m = t * 16 + mi;
        // cm word idx 3m: 16 lanes stride-3, gcd(3,32)=1 -> distinct banks;
        // the 4 k-groups share addresses -> broadcast, no conflict.
        const float dx = xn - cm[m*3+0];
        const float dy = yn - cm[m*3+1];
        const float dz = zn - cm[m*3+2];
        const float d2 = fmaf(dx, dx, fmaf(dy, dy, dz * dz));
        const float d  = __builtin_amdgcn_sqrtf(d2);   // raw v_sqrt_f32

        const float dd = d - mu0;
        float r  = __expf(-10.0f * dd * dd);    // r_{k0}
        float tt2 = __expf(2.0f * d - tcst);    // ratio t_{k0+1}

        f16x8 bfrag;                            // B[k = 8g+j][m = mi]
        bfrag[0] = (_Float16)r;
        #pragma unroll
        for (int j = 1; j < 8; ++j) {
            r *= tt2;                           // r_{k0+j}
            tt2 *= u;
            bfrag[j] = (_Float16)r;
        }

        f32x4 acc = cinit;                      // D = W * RBF^T + bias
        acc = __builtin_amdgcn_mfma_f32_16x16x32_f16(afrag, bfrag, acc, 0, 0, 0);

        // dense: out[b, n, m, 4g+0..3] -- one dwordx4, wave spans 1KB fully
        __builtin_nontemporal_store(acc,
            reinterpret_cast<f32x4*>(obase + (size_t)t * 16 * FOUT));
    }
}

extern "C" void kernel_launch(void* const* d_in, const int* in_sizes, int n_in,
                              void* d_out, int out_size, void* d_ws, size_t ws_size,
                              hipStream_t stream) {
    const float* coords = (const float*)d_in[0];
    const float* Ww     = (const float*)d_in[1];
    const float* Wb     = (const float*)d_in[2];
    float* out          = (float*)d_out;

    dim3 grid(NA, NB);   // (n, b)
    cfconv_kernel<<<grid, 256, 0, stream>>>(coords, Ww, Wb, out);
}